// Round 4
// baseline (1007.233 us; speedup 1.0000x reference)
//
#include <hip/hip_runtime.h>
#include <hip/hip_bf16.h>

// B=2, S=128, H=12, DH=64, HID=768
// scores(b,h,i,j) = dot64(q+ra, k+rb)/8 + mask ; t = h*16384+i*128+j ; r=t/12, c=t%12
// ra = ip[r, 64c+d], rb = ip[r, 768+64c+d], ip = inference_path @ Wip (bf16 MFMA, never materialized)

typedef __attribute__((ext_vector_type(8))) __bf16 bf16x8;
typedef __attribute__((ext_vector_type(16))) float f32x16;

// ws layout (total 7,208,960 B — same as proven R1 footprint)
#define QKV_OFF   0u         // [256][1536] f32 : q cols 0..767, k cols 768..1535
#define VT_OFF    1572864u   // [2][13][64][128] f32 (v heads 0..11, parse=12), [d][j]
#define ARENA_OFF 2424832u   // 2304 B-frags x 1KB bf16 (Wip), frag = n32*48 + k16
#define SC_OFF    4784128u   // [2][12][128][128] f32
#define CTX_OFF   6356992u   // [256][832] f32

// ---------------- prep: Wip [768][1536] f32 -> bf16 B-frags ----------------
// frag f = n32*48 + k16 ; lane l: col = n32*32+(l&31), k = k16*16+(l>>5)*8+j
__global__ __launch_bounds__(256)
void prep_kernel(const float* __restrict__ Wip, __bf16* __restrict__ arena) {
  const int l = threadIdx.x & 63;
  const int f = blockIdx.x * 4 + (threadIdx.x >> 6);   // 0..2303
  const int n32 = f / 48, k16 = f - n32 * 48;
  const float* src = Wip + (size_t)(k16 * 16 + (l >> 5) * 8) * 1536 + n32 * 32 + (l & 31);
  union { __bf16 h[8]; uint4 u; } pk;
#pragma unroll
  for (int j = 0; j < 8; j++) pk.h[j] = (__bf16)src[(size_t)j * 1536];
  ((uint4*)arena)[(size_t)f * 64 + l] = pk.u;
}

// ---------------- proj: [256x768]@[768x2368] bf16 MFMA, wave-blocks, K-split ----------------
// grid (37 n-tiles64, 8 m-tiles32, 2 k-halves) x 64 thr. atomicAdd into qkv / vT.
__global__ __launch_bounds__(64)
void proj_kernel(const float* __restrict__ hs,
                 const float* __restrict__ Wq, const float* __restrict__ bq,
                 const float* __restrict__ Wk, const float* __restrict__ bk,
                 const float* __restrict__ Wv, const float* __restrict__ bv,
                 const float* __restrict__ Wpv, const float* __restrict__ bpv,
                 float* __restrict__ qkv, float* __restrict__ vT) {
  const int n0 = blockIdx.x * 64;
  const int m0 = blockIdx.y * 32;
  const int kh = blockIdx.z;
  const float* W; const float* bias; int noff, ldw;
  if (n0 < 768)       { W = Wq;  bias = bq;  noff = n0;        ldw = 768; }
  else if (n0 < 1536) { W = Wk;  bias = bk;  noff = n0 - 768;  ldw = 768; }
  else if (n0 < 2304) { W = Wv;  bias = bv;  noff = n0 - 1536; ldw = 768; }
  else                { W = Wpv; bias = bpv; noff = 0;         ldw = 64;  }
  const int l = threadIdx.x;
  const int rsel = l & 31, ksel = l >> 5;
  f32x16 acc[2];
#pragma unroll
  for (int nt = 0; nt < 2; nt++)
#pragma unroll
    for (int z = 0; z < 16; z++) acc[nt][z] = 0.f;

#pragma unroll 4
  for (int kk = 0; kk < 24; kk++) {
    int k16 = kh * 24 + kk;
    const float* ap = hs + (size_t)(m0 + rsel) * 768 + k16 * 16 + ksel * 8;
    float4 a0 = *(const float4*)ap;
    float4 a1 = *(const float4*)(ap + 4);
    union { __bf16 h[8]; bf16x8 v; } pa;
    pa.h[0] = (__bf16)a0.x; pa.h[1] = (__bf16)a0.y; pa.h[2] = (__bf16)a0.z; pa.h[3] = (__bf16)a0.w;
    pa.h[4] = (__bf16)a1.x; pa.h[5] = (__bf16)a1.y; pa.h[6] = (__bf16)a1.z; pa.h[7] = (__bf16)a1.w;
#pragma unroll
    for (int nt = 0; nt < 2; nt++) {
      const float* bp = W + (size_t)(k16 * 16 + ksel * 8) * ldw + noff + nt * 32 + rsel;
      union { __bf16 h[8]; bf16x8 v; } pb;
#pragma unroll
      for (int j = 0; j < 8; j++) pb.h[j] = (__bf16)bp[(size_t)j * ldw];
      acc[nt] = __builtin_amdgcn_mfma_f32_32x32x16_bf16(pa.v, pb.v, acc[nt], 0, 0, 0);
    }
  }
#pragma unroll
  for (int nt = 0; nt < 2; nt++) {
    int ncol = nt * 32 + rsel;
#pragma unroll
    for (int reg = 0; reg < 16; reg++) {
      int row = (reg & 3) + ((reg >> 2) << 3) + ((l >> 5) << 2);
      int gm = m0 + row;
      float cv = acc[nt][reg] + (kh == 0 ? bias[noff + ncol] : 0.f);
      if (n0 < 1536) {
        atomicAdd(&qkv[(size_t)gm * 1536 + n0 + ncol], cv);
      } else {
        int vcol = noff + ncol;
        int hh = (n0 >= 2304) ? 12 : (vcol >> 6);
        int dd = (n0 >= 2304) ? vcol : (vcol & 63);
        atomicAdd(&vT[((size_t)((gm >> 7) * 13 + hh) * 64 + dd) * 128 + (gm & 127)], cv);
      }
    }
  }
}

// ---------------- score: fused ip-GEMM + score reduction ----------------
extern __shared__ char smem_raw[];

__global__ __launch_bounds__(512, 2)
void score_kernel(const float* __restrict__ infp,
                  const __bf16* __restrict__ arena,
                  const float* __restrict__ qkv,
                  float* __restrict__ scores) {
  char* Abase = smem_raw;                        // 96 frags * 1040 = 99840 B
  float* lds_sc = (float*)(smem_raw + 99840);    // 64*12 floats
  const int tid = threadIdx.x;
  const int lane = tid & 63;
  const int ml = lane & 31;
  const int kh = lane >> 5;
  const int wv = tid >> 6;
  const int wc = wv & 3;
  const int wd = wv >> 2;
  const int blk = blockIdx.x;
  const int b = blk >> 8;
  const int r0 = (blk & 255) << 6;

  for (int z = tid; z < 768; z += 512) lds_sc[z] = 0.f;

  // stage A: 64 rows x 768 f32 -> bf16 frag-ordered LDS (HBM read-once)
  {
    const float4* A4 = (const float4*)(infp + (size_t)(b * 16384 + r0) * 768);
#pragma unroll
    for (int p = 0; p < 12; p++) {
      int idx = p * 512 + tid;
      int m = (int)(((unsigned)idx * 10923u) >> 20);   // idx/96
      int g = idx - m * 96;
      float4 v0 = A4[m * 192 + g * 2];
      float4 v1 = A4[m * 192 + g * 2 + 1];
      union { __bf16 h[8]; uint4 u; } pk;
      pk.h[0] = (__bf16)v0.x; pk.h[1] = (__bf16)v0.y;
      pk.h[2] = (__bf16)v0.z; pk.h[3] = (__bf16)v0.w;
      pk.h[4] = (__bf16)v1.x; pk.h[5] = (__bf16)v1.y;
      pk.h[6] = (__bf16)v1.z; pk.h[7] = (__bf16)v1.w;
      int F = (m >> 5) * 48 + (g >> 1);
      int slot = (m & 31) + ((g & 1) << 5);
      *(uint4*)(Abase + ((F * 65 + slot) << 4)) = pk.u;
    }
  }
  __syncthreads();

  const size_t lane_off = (size_t)(lane << 4);
  const uint4* BA = (const uint4*)arena;
  auto loadB = [&](uint4* dst, int c, int kc) {
    const uint4* pa = BA + (size_t)(((2 * c + wd) * 48 + kc * 4) * 64) + lane;
#pragma unroll
    for (int ks = 0; ks < 4; ks++) {
      dst[ks * 2]     = pa[ks * 64];           // ra (cols < 768)
      dst[ks * 2 + 1] = pa[ks * 64 + 73728];   // rb (+1152 frags)
    }
  };
  auto loadA = [&](bf16x8 (*dst)[4], int kc) {
#pragma unroll
    for (int mt = 0; mt < 2; mt++)
#pragma unroll
      for (int ks = 0; ks < 4; ks++)
        dst[mt][ks] = *(const bf16x8*)(Abase + (((mt * 48 + kc * 4 + ks) * 65) << 4) + lane_off);
  };

  uint4 Bb[2][8];
  bf16x8 Aa[2][2][4];
  f32x16 acc_ra[2], acc_rb[2];
#pragma unroll
  for (int mt = 0; mt < 2; mt++)
#pragma unroll
    for (int z = 0; z < 16; z++) { acc_ra[mt][z] = 0.f; acc_rb[mt][z] = 0.f; }

  loadB(Bb[0], wc, 0);
  loadA(Aa[0], 0);

#pragma unroll
  for (int it = 0; it < 36; it++) {
    const int cur = it & 1, nxt = cur ^ 1;
    const int kc = it % 12;
    const int c = wc + (it / 12) * 4;
    if (it < 35) {
      const int kc1 = (it + 1) % 12;
      const int c1 = wc + ((it + 1) / 12) * 4;
      loadB(Bb[nxt], c1, kc1);
      loadA(Aa[nxt], kc1);
    }
#pragma unroll
    for (int ks = 0; ks < 4; ks++) {
      bf16x8 bra = *(bf16x8*)&Bb[cur][ks * 2];
      bf16x8 brb = *(bf16x8*)&Bb[cur][ks * 2 + 1];
#pragma unroll
      for (int mt = 0; mt < 2; mt++) {
        acc_ra[mt] = __builtin_amdgcn_mfma_f32_32x32x16_bf16(Aa[cur][mt][ks], bra, acc_ra[mt], 0, 0, 0);
        acc_rb[mt] = __builtin_amdgcn_mfma_f32_32x32x16_bf16(Aa[cur][mt][ks], brb, acc_rb[mt], 0, 0, 0);
      }
    }
    if (kc == 11) {
      int d = wd * 32 + ml;
#pragma unroll
      for (int mt = 0; mt < 2; mt++) {
        float qv[16], kv[16];
#pragma unroll
        for (int reg = 0; reg < 16; reg++) {
          int row = mt * 32 + (reg & 3) + ((reg >> 2) << 3) + (kh << 2);
          int t = 12 * (r0 + row) + c;
          int hh = t >> 14;
          int ii = (t >> 7) & 127;
          int jj = t & 127;
          qv[reg] = qkv[(size_t)((b << 7) + ii) * 1536 + (hh << 6) + d];
          kv[reg] = qkv[(size_t)((b << 7) + jj) * 1536 + 768 + (hh << 6) + d];
        }
#pragma unroll
        for (int reg = 0; reg < 16; reg++) {
          int row = mt * 32 + (reg & 3) + ((reg >> 2) << 3) + (kh << 2);
          float p = (qv[reg] + acc_ra[mt][reg]) * (kv[reg] + acc_rb[mt][reg]);
          p += __shfl_xor(p, 16);
          p += __shfl_xor(p, 8);
          p += __shfl_xor(p, 4);
          p += __shfl_xor(p, 2);
          p += __shfl_xor(p, 1);
          if (ml == 0) atomicAdd(&lds_sc[row * 12 + c], p);
        }
      }
#pragma unroll
      for (int mt = 0; mt < 2; mt++)
#pragma unroll
        for (int z = 0; z < 16; z++) { acc_ra[mt][z] = 0.f; acc_rb[mt][z] = 0.f; }
    }
  }

  __syncthreads();
  for (int z = tid; z < 768; z += 512) {
    int row = z / 12;
    int cc = z - row * 12;
    int t = 12 * (r0 + row) + cc;
    int hh = t >> 14;
    int ii = (t >> 7) & 127;
    int jj = t & 127;
    scores[(size_t)((b * 12 + hh) * 128 + ii) * 128 + jj] = lds_sc[z];
  }
}

// ---------------- attn: one (b,i) per block; softmax 13 rows + PV dots via vT ----------------
__global__ __launch_bounds__(256)
void attn_kernel(const float* __restrict__ scores, const float* __restrict__ vT,
                 const float* __restrict__ mask, const float* __restrict__ span,
                 float* __restrict__ ctx) {
  const int i = blockIdx.x;
  const int b = blockIdx.y;
  const int tid = threadIdx.x;
  const int l = tid & 63;
  const int wv = tid >> 6;
  __shared__ float w[13][132];
  for (int r = wv; r < 13; r += 4) {
    if (r < 12) {
      const float* sp = scores + (size_t)((b * 12 + r) * 128 + i) * 128;
      float s0 = sp[l] * 0.125f + mask[b * 128 + l];
      float s1 = sp[l + 64] * 0.125f + mask[b * 128 + l + 64];
      float mx = fmaxf(s0, s1);
#pragma unroll
      for (int o = 32; o; o >>= 1) mx = fmaxf(mx, __shfl_xor(mx, o));
      float e0 = __expf(s0 - mx), e1 = __expf(s1 - mx);
      float sm = e0 + e1;
#pragma unroll
      for (int o = 32; o; o >>= 1) sm += __shfl_xor(sm, o);
      float inv = 1.f / sm;
      w[r][l] = e0 * inv;
      w[r][l + 64] = e1 * inv;
    } else {
      const float* sp = span + (size_t)(b * 128 + i) * 128;
      w[12][l] = sp[l];
      w[12][l + 64] = sp[l + 64];
    }
  }
  __syncthreads();
  for (int o = tid; o < 832; o += 256) {
    int h = o >> 6, d = o & 63;
    const float4* vp = (const float4*)(vT + ((size_t)((b * 13 + h) * 64 + d)) * 128);
    const float4* wp = (const float4*)&w[h][0];
    float acc = 0.f;
#pragma unroll
    for (int j4 = 0; j4 < 32; j4++) {
      float4 vv = vp[j4];
      float4 ww = wp[j4];
      acc += ww.x * vv.x + ww.y * vv.y + ww.z * vv.z + ww.w * vv.w;
    }
    ctx[(size_t)(b * 128 + i) * 832 + o] = acc;
  }
}

// ---------------- out: [256x832]@[832x768] bf16 MFMA wave-blocks, K-split 4 ----------------
__global__ __launch_bounds__(64)
void out_kernel(const float* __restrict__ ctxb, const float* __restrict__ Wmlp,
                const float* __restrict__ bmlp, float* __restrict__ out) {
  const int n0 = blockIdx.x * 64;   // 12
  const int m0 = blockIdx.y * 32;   // 8
  const int kz = blockIdx.z;        // 4 -> k16 in [kz*13, +13)
  const int l = threadIdx.x;
  const int rsel = l & 31, ksel = l >> 5;
  f32x16 acc[2];
#pragma unroll
  for (int nt = 0; nt < 2; nt++)
#pragma unroll
    for (int z = 0; z < 16; z++) acc[nt][z] = 0.f;

#pragma unroll 4
  for (int kk = 0; kk < 13; kk++) {
    int k16 = kz * 13 + kk;
    const float* ap = ctxb + (size_t)(m0 + rsel) * 832 + k16 * 16 + ksel * 8;
    float4 a0 = *(const float4*)ap;
    float4 a1 = *(const float4*)(ap + 4);
    union { __bf16 h[8]; bf16x8 v; } pa;
    pa.h[0] = (__bf16)a0.x; pa.h[1] = (__bf16)a0.y; pa.h[2] = (__bf16)a0.z; pa.h[3] = (__bf16)a0.w;
    pa.h[4] = (__bf16)a1.x; pa.h[5] = (__bf16)a1.y; pa.h[6] = (__bf16)a1.z; pa.h[7] = (__bf16)a1.w;
#pragma unroll
    for (int nt = 0; nt < 2; nt++) {
      const float* bp = Wmlp + (size_t)(k16 * 16 + ksel * 8) * 768 + n0 + nt * 32 + rsel;
      union { __bf16 h[8]; bf16x8 v; } pb;
#pragma unroll
      for (int j = 0; j < 8; j++) pb.h[j] = (__bf16)bp[(size_t)j * 768];
      acc[nt] = __builtin_amdgcn_mfma_f32_32x32x16_bf16(pa.v, pb.v, acc[nt], 0, 0, 0);
    }
  }
#pragma unroll
  for (int nt = 0; nt < 2; nt++) {
    int ncol = nt * 32 + rsel;
#pragma unroll
    for (int reg = 0; reg < 16; reg++) {
      int row = (reg & 3) + ((reg >> 2) << 3) + ((l >> 5) << 2);
      float cv = acc[nt][reg] + (kz == 0 ? bmlp[n0 + ncol] : 0.f);
      atomicAdd(&out[(size_t)(m0 + row) * 768 + n0 + ncol], cv);
    }
  }
}

// ---------------- launch ----------------
extern "C" void kernel_launch(void* const* d_in, const int* in_sizes, int n_in,
                              void* d_out, int out_size, void* d_ws, size_t ws_size,
                              hipStream_t stream) {
  const float* hs   = (const float*)d_in[0];
  const float* mask = (const float*)d_in[1];
  const float* infp = (const float*)d_in[2];
  const float* span = (const float*)d_in[3];
  const float* Wq   = (const float*)d_in[4];
  const float* bq   = (const float*)d_in[5];
  const float* Wk   = (const float*)d_in[6];
  const float* bk   = (const float*)d_in[7];
  const float* Wv   = (const float*)d_in[8];
  const float* bv   = (const float*)d_in[9];
  const float* Wpv  = (const float*)d_in[10];
  const float* bpv  = (const float*)d_in[11];
  const float* Wip  = (const float*)d_in[12];
  const float* Wmlp = (const float*)d_in[13];
  const float* bmlp = (const float*)d_in[14];
  float* out = (float*)d_out;

  char* ws = (char*)d_ws;
  float*  qkv    = (float*)(ws + QKV_OFF);
  float*  vT     = (float*)(ws + VT_OFF);
  __bf16* arena  = (__bf16*)(ws + ARENA_OFF);
  float*  scores = (float*)(ws + SC_OFF);
  float*  ctx    = (float*)(ws + CTX_OFF);

  hipMemsetAsync(ws, 0, 2424832, stream);                 // qkv + vT
  hipMemsetAsync(out, 0, (size_t)out_size * 4, stream);   // out accumulators
  prep_kernel<<<dim3(576), 256, 0, stream>>>(Wip, arena);
  proj_kernel<<<dim3(37, 8, 2), 64, 0, stream>>>(hs, Wq, bq, Wk, bk, Wv, bv, Wpv, bpv, qkv, vT);
  score_kernel<<<dim3(512), 512, 102912, stream>>>(infp, arena, qkv, scores);
  attn_kernel<<<dim3(128, 2), 256, 0, stream>>>(scores, vT, mask, span, ctx);
  out_kernel<<<dim3(12, 8, 4), 64, 0, stream>>>(ctx, Wmlp, bmlp, out);
}

// Round 5
// 370.448 us; speedup vs baseline: 2.7190x; 2.7190x over previous
//
#include <hip/hip_runtime.h>
#include <hip/hip_bf16.h>

// B=2, S=128, H=12, DH=64, HID=768
// scores(b,h,i,j) = dot64(q+ra, k+rb)/8 + mask ; t = h*16384+i*128+j ; r=t/12, c=t%12
// ra = ip[r, 64c+d], rb = ip[r, 768+64c+d], ip = inference_path @ Wip (bf16 MFMA, never materialized)

typedef __attribute__((ext_vector_type(8))) __bf16 bf16x8;
typedef __attribute__((ext_vector_type(16))) float f32x16;

// ws layout (total 7,208,960 B — proven footprint)
#define QKV_OFF   0u         // [256][2368] f32 : q|k|v|pv
#define ARENA_OFF 2424832u   // 2304 B-frags x 1KB bf16 (Wip), frag = n32*48 + k16
#define SC_OFF    4784128u   // [2][12][128][128] f32
#define CTX_OFF   6356992u   // [256][832] f32

// ---------------- prep: Wip [768][1536] f32 -> bf16 B-frags ----------------
// frag f = n32*48 + k16 ; lane l: col = n32*32+(l&31), k = k16*16+(l>>5)*8+j
__global__ __launch_bounds__(256)
void prep_kernel(const float* __restrict__ Wip, __bf16* __restrict__ arena) {
  const int l = threadIdx.x & 63;
  const int f = blockIdx.x * 4 + (threadIdx.x >> 6);   // 0..2303
  const int n32 = f / 48, k16 = f - n32 * 48;
  const float* src = Wip + (size_t)(k16 * 16 + (l >> 5) * 8) * 1536 + n32 * 32 + (l & 31);
  union { __bf16 h[8]; uint4 u; } pk;
#pragma unroll
  for (int j = 0; j < 8; j++) pk.h[j] = (__bf16)src[(size_t)j * 1536];
  ((uint4*)arena)[(size_t)f * 64 + l] = pk.u;
}

// ---------------- proj: wave-block MFMA GEMM, full K, direct stores ----------------
// grid (74 n32-tiles, 8 m32-tiles) x 64 thr.
__global__ __launch_bounds__(64)
void proj_kernel(const float* __restrict__ hs,
                 const float* __restrict__ Wq, const float* __restrict__ bq,
                 const float* __restrict__ Wk, const float* __restrict__ bk,
                 const float* __restrict__ Wv, const float* __restrict__ bv,
                 const float* __restrict__ Wpv, const float* __restrict__ bpv,
                 float* __restrict__ qkv) {
  const int n0 = blockIdx.x * 32;   // combined col space [q|k|v|pv] = 2368
  const int m0 = blockIdx.y * 32;
  const float* W; const float* bias; int noff, ldw;
  if (n0 < 768)       { W = Wq;  bias = bq;  noff = n0;        ldw = 768; }
  else if (n0 < 1536) { W = Wk;  bias = bk;  noff = n0 - 768;  ldw = 768; }
  else if (n0 < 2304) { W = Wv;  bias = bv;  noff = n0 - 1536; ldw = 768; }
  else                { W = Wpv; bias = bpv; noff = n0 - 2304; ldw = 64;  }
  const int l = threadIdx.x;
  const int rsel = l & 31, ksel = l >> 5;
  f32x16 acc;
#pragma unroll
  for (int z = 0; z < 16; z++) acc[z] = 0.f;

#pragma unroll 4
  for (int k16 = 0; k16 < 48; k16++) {
    const float* ap = hs + (size_t)(m0 + rsel) * 768 + k16 * 16 + ksel * 8;
    float4 a0 = *(const float4*)ap;
    float4 a1 = *(const float4*)(ap + 4);
    union { __bf16 h[8]; bf16x8 v; } pa;
    pa.h[0] = (__bf16)a0.x; pa.h[1] = (__bf16)a0.y; pa.h[2] = (__bf16)a0.z; pa.h[3] = (__bf16)a0.w;
    pa.h[4] = (__bf16)a1.x; pa.h[5] = (__bf16)a1.y; pa.h[6] = (__bf16)a1.z; pa.h[7] = (__bf16)a1.w;
    const float* bp = W + (size_t)(k16 * 16 + ksel * 8) * ldw + noff + rsel;
    union { __bf16 h[8]; bf16x8 v; } pb;
#pragma unroll
    for (int j = 0; j < 8; j++) pb.h[j] = (__bf16)bp[(size_t)j * ldw];
    acc = __builtin_amdgcn_mfma_f32_32x32x16_bf16(pa.v, pb.v, acc, 0, 0, 0);
  }
#pragma unroll
  for (int reg = 0; reg < 16; reg++) {
    int row = (reg & 3) + ((reg >> 2) << 3) + (ksel << 2);
    qkv[(size_t)(m0 + row) * 2368 + n0 + rsel] = acc[reg] + bias[noff + rsel];
  }
}

// ---------------- score: fused ip-GEMM + score reduction, pipelined rolled K-loop ----------------
extern __shared__ char smem_raw[];

__global__ __launch_bounds__(512, 2)
void score_kernel(const float* __restrict__ infp,
                  const __bf16* __restrict__ arena,
                  const float* __restrict__ qkv,
                  float* __restrict__ scores) {
  char* Abase = smem_raw;                        // 96 frags * 1040 = 99840 B
  float* lds_sc = (float*)(smem_raw + 99840);    // 64*12 floats
  const int tid = threadIdx.x;
  const int lane = tid & 63;
  const int ml = lane & 31;
  const int kh = lane >> 5;
  const int wv = tid >> 6;
  const int wc = wv & 3;
  const int wd = wv >> 2;
  const int blk = blockIdx.x;
  const int b = blk >> 8;
  const int r0 = (blk & 255) << 6;

  for (int z = tid; z < 768; z += 512) lds_sc[z] = 0.f;

  // stage A: 64 rows x 768 f32 -> bf16 frag-ordered LDS (HBM read-once)
  {
    const float4* A4 = (const float4*)(infp + (size_t)(b * 16384 + r0) * 768);
#pragma unroll
    for (int p = 0; p < 12; p++) {
      int idx = p * 512 + tid;
      int m = (int)(((unsigned)idx * 10923u) >> 20);   // idx/96
      int g = idx - m * 96;
      float4 v0 = A4[m * 192 + g * 2];
      float4 v1 = A4[m * 192 + g * 2 + 1];
      union { __bf16 h[8]; uint4 u; } pk;
      pk.h[0] = (__bf16)v0.x; pk.h[1] = (__bf16)v0.y;
      pk.h[2] = (__bf16)v0.z; pk.h[3] = (__bf16)v0.w;
      pk.h[4] = (__bf16)v1.x; pk.h[5] = (__bf16)v1.y;
      pk.h[6] = (__bf16)v1.z; pk.h[7] = (__bf16)v1.w;
      int F = (m >> 5) * 48 + (g >> 1);
      int slot = (m & 31) + ((g & 1) << 5);
      *(uint4*)(Abase + ((F * 65 + slot) << 4)) = pk.u;
    }
  }
  __syncthreads();

  const size_t lane_off = (size_t)(lane << 4);
  const uint4* BA = (const uint4*)arena;
  uint4 B0[8], B1[8];
  bf16x8 Af[8];
  f32x16 acc_ra[2], acc_rb[2];

  auto loadB = [&](uint4* dst, int c, int kc) {
    const uint4* pa = BA + (size_t)(((2 * c + wd) * 48 + kc * 4) * 64) + lane;
#pragma unroll
    for (int ks = 0; ks < 4; ks++) {
      dst[ks * 2]     = pa[ks * 64];           // ra (cols < 768)
      dst[ks * 2 + 1] = pa[ks * 64 + 73728];   // rb (+1152 frags)
    }
  };
  auto loadA = [&](int kc) {
#pragma unroll
    for (int mt = 0; mt < 2; mt++)
#pragma unroll
      for (int ks = 0; ks < 4; ks++)
        Af[mt * 4 + ks] = *(const bf16x8*)(Abase + (((mt * 48 + kc * 4 + ks) * 65) << 4) + lane_off);
  };
  auto mfma_step = [&](uint4* Bb) {
#pragma unroll
    for (int ks = 0; ks < 4; ks++) {
      bf16x8 bra = *(bf16x8*)&Bb[ks * 2];
      bf16x8 brb = *(bf16x8*)&Bb[ks * 2 + 1];
#pragma unroll
      for (int mt = 0; mt < 2; mt++) {
        acc_ra[mt] = __builtin_amdgcn_mfma_f32_32x32x16_bf16(Af[mt * 4 + ks], bra, acc_ra[mt], 0, 0, 0);
        acc_rb[mt] = __builtin_amdgcn_mfma_f32_32x32x16_bf16(Af[mt * 4 + ks], brb, acc_rb[mt], 0, 0, 0);
      }
    }
  };
  auto epilogue = [&](int c) {
    int d = wd * 32 + ml;
#pragma unroll
    for (int mt = 0; mt < 2; mt++) {
      float qv[16], kv[16];
#pragma unroll
      for (int reg = 0; reg < 16; reg++) {
        int row = mt * 32 + (reg & 3) + ((reg >> 2) << 3) + (kh << 2);
        int t = 12 * (r0 + row) + c;
        int hh = t >> 14;
        int ii = (t >> 7) & 127;
        int jj = t & 127;
        qv[reg] = qkv[(size_t)((b << 7) + ii) * 2368 + (hh << 6) + d];
        kv[reg] = qkv[(size_t)((b << 7) + jj) * 2368 + 768 + (hh << 6) + d];
      }
#pragma unroll
      for (int reg = 0; reg < 16; reg++) {
        int row = mt * 32 + (reg & 3) + ((reg >> 2) << 3) + (kh << 2);
        float p = (qv[reg] + acc_ra[mt][reg]) * (kv[reg] + acc_rb[mt][reg]);
        p += __shfl_xor(p, 16);
        p += __shfl_xor(p, 8);
        p += __shfl_xor(p, 4);
        p += __shfl_xor(p, 2);
        p += __shfl_xor(p, 1);
        if (ml == 0) atomicAdd(&lds_sc[row * 12 + c], p);
      }
    }
#pragma unroll
    for (int mt = 0; mt < 2; mt++)
#pragma unroll
      for (int z = 0; z < 16; z++) { acc_ra[mt][z] = 0.f; acc_rb[mt][z] = 0.f; }
  };

#pragma unroll
  for (int mt = 0; mt < 2; mt++)
#pragma unroll
    for (int z = 0; z < 16; z++) { acc_ra[mt][z] = 0.f; acc_rb[mt][z] = 0.f; }

  loadB(B0, wc, 0);
  int kc = 0, c = wc;
#pragma unroll 1
  for (int ith = 0; ith < 18; ith++) {
    // even slot: consume B0, prefetch B1 (kc here is even, never 11)
    {
      int kcn = kc + 1, cn = c;
      if (kcn == 12) { kcn = 0; cn = c + 4; }
      loadA(kc);
      loadB(B1, cn, kcn);
      __builtin_amdgcn_sched_barrier(0);
      mfma_step(B0);
      kc = kcn; c = cn;
    }
    // odd slot: consume B1, prefetch B0; epilogue when kc==11
    {
      int kcn = kc + 1, cn = c;
      if (kcn == 12) { kcn = 0; cn = c + 4; }
      loadA(kc);
      if (ith < 17) loadB(B0, cn, kcn);
      __builtin_amdgcn_sched_barrier(0);
      mfma_step(B1);
      if (kc == 11) epilogue(c);
      kc = kcn; c = cn;
    }
  }

  __syncthreads();
  for (int z = tid; z < 768; z += 512) {
    int row = z / 12;
    int cc = z - row * 12;
    int t = 12 * (r0 + row) + cc;
    int hh = t >> 14;
    int ii = (t >> 7) & 127;
    int jj = t & 127;
    scores[(size_t)((b * 12 + hh) * 128 + ii) * 128 + jj] = lds_sc[z];
  }
}

// ---------------- attn: one (b,i) per block; softmax 13 rows + PV dots from qkv ----------------
__global__ __launch_bounds__(256)
void attn_kernel(const float* __restrict__ scores, const float* __restrict__ qkv,
                 const float* __restrict__ mask, const float* __restrict__ span,
                 float* __restrict__ ctx) {
  const int i = blockIdx.x;
  const int b = blockIdx.y;
  const int tid = threadIdx.x;
  const int l = tid & 63;
  const int wvi = tid >> 6;
  __shared__ float w[13][132];
  for (int r = wvi; r < 13; r += 4) {
    if (r < 12) {
      const float* sp = scores + (size_t)((b * 12 + r) * 128 + i) * 128;
      float s0 = sp[l] * 0.125f + mask[b * 128 + l];
      float s1 = sp[l + 64] * 0.125f + mask[b * 128 + l + 64];
      float mx = fmaxf(s0, s1);
#pragma unroll
      for (int o = 32; o; o >>= 1) mx = fmaxf(mx, __shfl_xor(mx, o));
      float e0 = __expf(s0 - mx), e1 = __expf(s1 - mx);
      float sm = e0 + e1;
#pragma unroll
      for (int o = 32; o; o >>= 1) sm += __shfl_xor(sm, o);
      float inv = 1.f / sm;
      w[r][l] = e0 * inv;
      w[r][l + 64] = e1 * inv;
    } else {
      const float* sp = span + (size_t)(b * 128 + i) * 128;
      w[12][l] = sp[l];
      w[12][l + 64] = sp[l + 64];
    }
  }
  __syncthreads();
  for (int o = tid; o < 832; o += 256) {
    int h = o >> 6, d = o & 63;
    const float* vp = qkv + (size_t)(b * 128) * 2368 + (h < 12 ? 1536 + h * 64 : 2304) + d;
    float acc = 0.f;
#pragma unroll 8
    for (int j = 0; j < 128; j++) acc += w[h][j] * vp[(size_t)j * 2368];
    ctx[(size_t)(b * 128 + i) * 832 + o] = acc;
  }
}

// ---------------- out: wave-block MFMA GEMM, full K, direct stores ----------------
// grid (24 n32, 8 m32) x 64 thr. ctx[256x832] @ Wmlp[832x768] + bmlp.
__global__ __launch_bounds__(64)
void out_kernel(const float* __restrict__ ctxb, const float* __restrict__ Wmlp,
                const float* __restrict__ bmlp, float* __restrict__ out) {
  const int n0 = blockIdx.x * 32;
  const int m0 = blockIdx.y * 32;
  const int l = threadIdx.x;
  const int rsel = l & 31, ksel = l >> 5;
  f32x16 acc;
#pragma unroll
  for (int z = 0; z < 16; z++) acc[z] = 0.f;

#pragma unroll 4
  for (int k16 = 0; k16 < 52; k16++) {
    const float* ap = ctxb + (size_t)(m0 + rsel) * 832 + k16 * 16 + ksel * 8;
    float4 a0 = *(const float4*)ap;
    float4 a1 = *(const float4*)(ap + 4);
    union { __bf16 h[8]; bf16x8 v; } pa;
    pa.h[0] = (__bf16)a0.x; pa.h[1] = (__bf16)a0.y; pa.h[2] = (__bf16)a0.z; pa.h[3] = (__bf16)a0.w;
    pa.h[4] = (__bf16)a1.x; pa.h[5] = (__bf16)a1.y; pa.h[6] = (__bf16)a1.z; pa.h[7] = (__bf16)a1.w;
    const float* bp = Wmlp + (size_t)(k16 * 16 + ksel * 8) * 768 + n0 + rsel;
    union { __bf16 h[8]; bf16x8 v; } pb;
#pragma unroll
    for (int j = 0; j < 8; j++) pb.h[j] = (__bf16)bp[(size_t)j * 768];
    acc = __builtin_amdgcn_mfma_f32_32x32x16_bf16(pa.v, pb.v, acc, 0, 0, 0);
  }
#pragma unroll
  for (int reg = 0; reg < 16; reg++) {
    int row = (reg & 3) + ((reg >> 2) << 3) + (ksel << 2);
    out[(size_t)(m0 + row) * 768 + n0 + rsel] = acc[reg] + bmlp[n0 + rsel];
  }
}

// ---------------- launch ----------------
extern "C" void kernel_launch(void* const* d_in, const int* in_sizes, int n_in,
                              void* d_out, int out_size, void* d_ws, size_t ws_size,
                              hipStream_t stream) {
  const float* hs   = (const float*)d_in[0];
  const float* mask = (const float*)d_in[1];
  const float* infp = (const float*)d_in[2];
  const float* span = (const float*)d_in[3];
  const float* Wq   = (const float*)d_in[4];
  const float* bq   = (const float*)d_in[5];
  const float* Wk   = (const float*)d_in[6];
  const float* bk   = (const float*)d_in[7];
  const float* Wv   = (const float*)d_in[8];
  const float* bv   = (const float*)d_in[9];
  const float* Wpv  = (const float*)d_in[10];
  const float* bpv  = (const float*)d_in[11];
  const float* Wip  = (const float*)d_in[12];
  const float* Wmlp = (const float*)d_in[13];
  const float* bmlp = (const float*)d_in[14];
  float* out = (float*)d_out;

  char* ws = (char*)d_ws;
  float*  qkv    = (float*)(ws + QKV_OFF);
  __bf16* arena  = (__bf16*)(ws + ARENA_OFF);
  float*  scores = (float*)(ws + SC_OFF);
  float*  ctx    = (float*)(ws + CTX_OFF);

  prep_kernel<<<dim3(576), 256, 0, stream>>>(Wip, arena);
  proj_kernel<<<dim3(74, 8), 64, 0, stream>>>(hs, Wq, bq, Wk, bk, Wv, bv, Wpv, bpv, qkv);
  score_kernel<<<dim3(512), 512, 102912, stream>>>(infp, arena, qkv, scores);
  attn_kernel<<<dim3(128, 2), 256, 0, stream>>>(scores, qkv, mask, span, ctx);
  out_kernel<<<dim3(24, 8), 64, 0, stream>>>(ctx, Wmlp, bmlp, out);
}